// Round 1
// baseline (1131.691 us; speedup 1.0000x reference)
//
#include <hip/hip_runtime.h>
#include <hip/hip_bf16.h>
#include <cstdint>
#include <cstddef>

// Problem constants (reference: N=8192, C=512, H=8)
#define NN 8192
#define CC 512
#define HH 8

typedef __attribute__((ext_vector_type(8))) short short8;   // 8 bf16 = 4 VGPRs
typedef __attribute__((ext_vector_type(4))) float f32x4;

enum { EPI_SPLIT = 0, EPI_BF16B = 1, EPI_EXP = 2, EPI_OUT = 3 };

__device__ __forceinline__ void gload_lds16(const void* g, void* l) {
  __builtin_amdgcn_global_load_lds(
      (const __attribute__((address_space(1))) void*)g,
      (__attribute__((address_space(3))) void*)l, 16, 0, 0);
}

__device__ __forceinline__ float b2f(unsigned short u) {
  union { unsigned int i; float f; } x; x.i = ((unsigned)u) << 16; return x.f;
}

// Universal C = sum_p A_p * B_p^T GEMM. A: M x K (lda), B: N x K (ldb), C: M x N.
// 128x128 block tile, 256 threads = 4 waves in 2x2, each wave 64x64 via 4x4
// mfma_f32_16x16x32_bf16. Staging via global_load_lds width=16 (m97 ladder).
// All dims assumed multiples of 128 (true here: 8192/4096/1024), K mult of 32.
template <int EPI, int NPROD>
__global__ __launch_bounds__(256, 2) void gemm_bt(
    const __hip_bfloat16* __restrict__ a0, const __hip_bfloat16* __restrict__ a1,
    const __hip_bfloat16* __restrict__ a2, int lda,
    const __hip_bfloat16* __restrict__ b0, const __hip_bfloat16* __restrict__ b1,
    const __hip_bfloat16* __restrict__ b2, int ldb,
    int K,
    __hip_bfloat16* __restrict__ outHi, __hip_bfloat16* __restrict__ outLo, int ldc,
    const float* __restrict__ biasRow, const float* __restrict__ biasCol,
    const float* __restrict__ Lrow, float* __restrict__ dout)
{
  __shared__ __align__(16) char lds[16384];  // A tile 8KB + B tile 8KB
  const int tid  = threadIdx.x;
  const int lane = tid & 63;
  const int wave = tid >> 6;
  const int bm = blockIdx.y, bn = blockIdx.x;
  const int wr = wave >> 1, wc = wave & 1;   // 2x2 wave grid
  const int fr = lane & 15, fq = lane >> 4;  // fragment row / quad

  f32x4 acc[4][4] = {};

  for (int p = 0; p < NPROD; ++p) {
    const __hip_bfloat16* A = (p == 0) ? a0 : ((p == 1) ? a1 : a2);
    const __hip_bfloat16* B = (p == 0) ? b0 : ((p == 1) ? b1 : b2);
    const __hip_bfloat16* Abase = A + (size_t)bm * 128 * lda;
    const __hip_bfloat16* Bbase = B + (size_t)bn * 128 * ldb;
    for (int kt = 0; kt < K; kt += 32) {
      __syncthreads();  // previous tile's LDS reads done
      // Stage A,B tiles (128 rows x 32 bf16 = 64B/row; 512 x 16B chunks each).
      // LDS dest = wave-uniform base + lane*16 -> layout is lane-linear row-major.
#pragma unroll
      for (int i = 0; i < 2; ++i) {
        int idx = i * 256 + tid;
        int row = idx >> 2, ch = idx & 3;
        gload_lds16(Abase + (size_t)row * lda + kt + ch * 8,
                    lds + (i * 256 + wave * 64) * 16);
        gload_lds16(Bbase + (size_t)row * ldb + kt + ch * 8,
                    lds + 8192 + (i * 256 + wave * 64) * 16);
      }
      __syncthreads();  // staging complete (implies vmcnt drain)

      short8 af[4], bfr[4];
#pragma unroll
      for (int i = 0; i < 4; ++i) {
        af[i]  = *(const short8*)(lds +        (wr * 64 + i * 16 + fr) * 64 + fq * 16);
        bfr[i] = *(const short8*)(lds + 8192 + (wc * 64 + i * 16 + fr) * 64 + fq * 16);
      }
#pragma unroll
      for (int i = 0; i < 4; ++i)
#pragma unroll
        for (int j = 0; j < 4; ++j)
          acc[i][j] = __builtin_amdgcn_mfma_f32_16x16x32_bf16(af[i], bfr[j], acc[i][j], 0, 0, 0);
    }
  }

  // Epilogue. C/D layout: col = lane&15, row = (lane>>4)*4 + t  [m89-verified]
#pragma unroll
  for (int i = 0; i < 4; ++i) {
#pragma unroll
    for (int j = 0; j < 4; ++j) {
      const int rbase = bm * 128 + wr * 64 + i * 16 + fq * 4;
      const int col   = bn * 128 + wc * 64 + j * 16 + fr;
#pragma unroll
      for (int t = 0; t < 4; ++t) {
        const int row = rbase + t;
        float v = acc[i][j][t];
        if constexpr (EPI == EPI_SPLIT) {
          // Q/K projection: split fp32 -> bf16 hi + lo residual
          v += biasCol[col];
          __hip_bfloat16 h = __float2bfloat16(v);
          outHi[(size_t)row * ldc + col] = h;
          outLo[(size_t)row * ldc + col] = __float2bfloat16(v - __bfloat162float(h));
        } else if constexpr (EPI == EPI_BF16B) {
          // XKT: bias indexed by output ROW (feature j = h*512+d)
          v += biasRow[row];
          outHi[(size_t)row * ldc + col] = __float2bfloat16(v);
        } else if constexpr (EPI == EPI_EXP) {
          // P = exp(sim - 64), unnormalized softmax numerator (bf16-safe range)
          outHi[(size_t)row * ldc + col] = __float2bfloat16(__expf(v - 64.0f));
        } else {  // EPI_OUT: relu(acc)/(8*L[row]) accumulated over heads
          float s = fmaxf(v, 0.0f) * (0.125f / Lrow[row]);
          atomicAdd(dout + (size_t)row * CC + (col & (CC - 1)), s);
        }
      }
    }
  }
}

// x (fp32) -> bf16 hi + lo residual
__global__ void split_kernel(const float* __restrict__ x,
                             __hip_bfloat16* __restrict__ hi,
                             __hip_bfloat16* __restrict__ lo, int n) {
  int i = blockIdx.x * 256 + threadIdx.x;
  if (i < n) {
    float v = x[i];
    __hip_bfloat16 h = __float2bfloat16(v);
    hi[i] = h;
    lo[i] = __float2bfloat16(v - __bfloat162float(h));
  }
}

// WT[j][c] = (j<512 ? W_theta : W_phi)[c][j&511], split hi/lo. 1024x512.
__global__ void build_wt(const float* __restrict__ Wth, const float* __restrict__ Wph,
                         __hip_bfloat16* __restrict__ wthi, __hip_bfloat16* __restrict__ wtlo) {
  int idx = blockIdx.x * 256 + threadIdx.x;  // 524288
  int j = idx >> 9, c = idx & 511;
  const float* W = (j < 512) ? Wth : Wph;
  float v = W[(size_t)c * 512 + (j & 511)];
  __hip_bfloat16 h = __float2bfloat16(v);
  wthi[idx] = h;
  wtlo[idx] = __float2bfloat16(v - __bfloat162float(h));
}

// WkT[j=h*512+d][c] = W_k[h][c][d], bf16. 4096x512.
__global__ void build_wkt(const float* __restrict__ Wk, __hip_bfloat16* __restrict__ wkt) {
  int idx = blockIdx.x * 256 + threadIdx.x;  // 2097152
  int j = idx >> 9, c = idx & 511;
  float v = Wk[(size_t)(j >> 9) * 262144 + (size_t)c * 512 + (j & 511)];
  wkt[idx] = __float2bfloat16(v);
}

__global__ void build_biasqk(const float* __restrict__ bt, const float* __restrict__ bp,
                             float* __restrict__ bias) {
  int i = blockIdx.x * 256 + threadIdx.x;  // 1024
  bias[i] = (i < 512) ? bt[i] : bp[i - 512];
}

// L[n] = sum_m P[n][m]
__global__ __launch_bounds__(256) void rowsum(const __hip_bfloat16* __restrict__ P,
                                              float* __restrict__ L) {
  const int n = blockIdx.x;
  const ushort4* r4 = (const ushort4*)(P + (size_t)n * NN);
  float s = 0.f;
  for (int i = threadIdx.x; i < NN / 4; i += 256) {
    ushort4 u = r4[i];
    s += b2f(u.x) + b2f(u.y) + b2f(u.z) + b2f(u.w);
  }
#pragma unroll
  for (int off = 32; off; off >>= 1) s += __shfl_down(s, off);
  __shared__ float wsum[4];
  if ((threadIdx.x & 63) == 0) wsum[threadIdx.x >> 6] = s;
  __syncthreads();
  if (threadIdx.x == 0) L[n] = wsum[0] + wsum[1] + wsum[2] + wsum[3];
}

extern "C" void kernel_launch(void* const* d_in, const int* in_sizes, int n_in,
                              void* d_out, int out_size, void* d_ws, size_t ws_size,
                              hipStream_t stream) {
  const float* x  = (const float*)d_in[0];
  const float* Wt = (const float*)d_in[1];
  const float* bt = (const float*)d_in[2];
  const float* Wp = (const float*)d_in[3];
  const float* bp = (const float*)d_in[4];
  const float* Wk = (const float*)d_in[5];
  const float* bk = (const float*)d_in[6];
  float* out = (float*)d_out;

  // Workspace layout (~246 MiB total)
  char* w = (char*)d_ws;
  __hip_bfloat16* P    = (__hip_bfloat16*)w; w += (size_t)NN * NN * 2;        // 128 MiB
  __hip_bfloat16* XKT  = (__hip_bfloat16*)w; w += (size_t)HH * CC * NN * 2;   // 64 MiB
  __hip_bfloat16* QKhi = (__hip_bfloat16*)w; w += (size_t)NN * 1024 * 2;      // 16 MiB
  __hip_bfloat16* QKlo = (__hip_bfloat16*)w; w += (size_t)NN * 1024 * 2;      // 16 MiB
  __hip_bfloat16* xhi  = (__hip_bfloat16*)w; w += (size_t)NN * CC * 2;        // 8 MiB
  __hip_bfloat16* xlo  = (__hip_bfloat16*)w; w += (size_t)NN * CC * 2;        // 8 MiB
  __hip_bfloat16* WkT  = (__hip_bfloat16*)w; w += (size_t)HH * CC * CC * 2;   // 4 MiB
  __hip_bfloat16* WThi = (__hip_bfloat16*)w; w += (size_t)1024 * CC * 2;      // 1 MiB
  __hip_bfloat16* WTlo = (__hip_bfloat16*)w; w += (size_t)1024 * CC * 2;      // 1 MiB
  float* biasqk = (float*)w; w += 4096;
  float* L      = (float*)w; w += NN * 4;

  // 1. preprocessing
  split_kernel<<<(NN * CC + 255) / 256, 256, 0, stream>>>(x, xhi, xlo, NN * CC);
  build_wt<<<(1024 * CC) / 256, 256, 0, stream>>>(Wt, Wp, WThi, WTlo);
  build_wkt<<<(HH * CC * CC) / 256, 256, 0, stream>>>(Wk, WkT);
  build_biasqk<<<4, 256, 0, stream>>>(bt, bp, biasqk);
  hipMemsetAsync(d_out, 0, (size_t)out_size * 4, stream);

  // 2. [Q|K] = x @ [W_theta|W_phi] with split precision (3 products), split output
  gemm_bt<EPI_SPLIT, 3><<<dim3(1024 / 128, NN / 128), 256, 0, stream>>>(
      xhi, xhi, xlo, CC, WThi, WTlo, WThi, CC, CC,
      QKhi, QKlo, 1024, nullptr, biasqk, nullptr, nullptr);

  // 3. XKT[j][m] = sum_c WkT[j][c] * x[m][c] + b_k[j]   (4096 x 8192)
  gemm_bt<EPI_BF16B, 1><<<dim3(NN / 128, (HH * CC) / 128), 256, 0, stream>>>(
      WkT, nullptr, nullptr, CC, xhi, nullptr, nullptr, CC, CC,
      XKT, nullptr, NN, bk, nullptr, nullptr, nullptr);

  // 4. P = exp(Q @ K^T - 64), split-precision 3-product (hi*hi + hi*lo + lo*hi)
  gemm_bt<EPI_EXP, 3><<<dim3(NN / 128, NN / 128), 256, 0, stream>>>(
      QKhi, QKhi, QKlo, 1024, QKhi + 512, QKlo + 512, QKhi + 512, 1024, CC,
      P, nullptr, NN, nullptr, nullptr, nullptr, nullptr);

  // 5. L = rowsum(P)
  rowsum<<<NN, 256, 0, stream>>>(P, L);

  // 6. out[n][d] += relu(P @ XKT^T)[n][h*512+d] / (8 * L[n])   over 8 heads
  gemm_bt<EPI_OUT, 1><<<dim3((HH * CC) / 128, NN / 128), 256, 0, stream>>>(
      P, nullptr, nullptr, NN, XKT, nullptr, nullptr, NN, NN,
      nullptr, nullptr, 0, nullptr, nullptr, L, out);
}